// Round 10
// baseline (325.433 us; speedup 1.0000x reference)
//
#include <hip/hip_runtime.h>

#define HW_   50176      // 224*224
#define PSTR_ 196608     // 64*32*32*3 floats per image

__device__ __forceinline__ float fpow(float x, float e) {
    // x > 0 guaranteed by callers; v_log_f32 is log2, v_exp_f32 is exp2
    return __builtin_amdgcn_exp2f(e * __builtin_amdgcn_logf(x));
}

__device__ __forceinline__ float srgb_lin(float c) {
    return c < 0.04045f ? c * (1.0f / 12.92f)
                        : fpow((c + 0.055f) * (1.0f / 1.055f), 2.4f);
}

__device__ __forceinline__ float enc_srgb(float c) {
    float e = (c < 0.0031308f)
                  ? 12.92f * c
                  : 1.055f * fpow(fmaxf(c, 1e-10f), 1.0f / 2.4f) - 0.055f;
    return fminf(fmaxf(e, 0.0f), 1.0f);
}

// L2-direct load (bypass L1 miss path): agent-scope relaxed atomic load.
__device__ __forceinline__ float ld_l2(const float* p) {
    return __hip_atomic_load(p, __ATOMIC_RELAXED, __HIP_MEMORY_SCOPE_AGENT);
}

__global__ __launch_bounds__(256) void cieluv_k10(
    const float* __restrict__ imgs,
    const float* __restrict__ params,
    float* __restrict__ out)
{
    // XCD-chunk swizzle (bijective: gridDim.x=12544 divisible by 8)
    int bid = blockIdx.x;
    int cpx = gridDim.x >> 3;                 // 1568
    int b   = (bid & 7) * cpx + (bid >> 3);

    int vi = b * 256 + threadIdx.x;           // pixel index (1 px/thread)
    int n  = vi / HW_;                        // image
    int pv = vi - n * HW_;                    // pixel offset within plane

    const float* img = imgs + (size_t)n * (3 * HW_) + pv;
    float rr_in = img[0];
    float gg_in = img[HW_];
    float bb_in = img[2 * HW_];
    const float* __restrict__ plist = params + (size_t)n * PSTR_;

    // ---- sRGB -> linear ----
    float r = srgb_lin(rr_in);
    float g = srgb_lin(gg_in);
    float bl = srgb_lin(bb_in);
    // ---- linear RGB -> XYZ ----
    float x = 0.4124f * r + 0.3576f * g + 0.1805f * bl;
    float y = 0.2126f * r + 0.7152f * g + 0.0722f * bl;
    float z = 0.0193f * r + 0.1192f * g + 0.9504f * bl;
    // ---- XYZ -> LUV (normalized) ----
    float inv = 1.0f / (x + 15.0f * y + 3.0f * z + 1e-10f);
    float up = 4.0f * x * inv;
    float vp = 9.0f * y * inv;
    float L = (y < 0.008856451679035631f)
                  ? 903.2962962962963f * y
                  : 116.0f * fpow(fmaxf(y, 1e-10f), 1.0f / 3.0f) - 16.0f;
    float u = 13.0f * L * (up - 0.1978f);
    float v = 13.0f * L * (vp - 0.4683f);
    float c0 = L * 0.01f;
    float c1 = (u + 100.0f) * 0.005f;
    float c2 = (v + 100.0f) * 0.005f;
    // ---- trilinear LUT (RX=64, RY=32, RZ=32) ----
    float s0 = c0 * 63.0f, s1 = c1 * 31.0f, s2 = c2 * 31.0f;
    float f0 = floorf(s0), f1 = floorf(s1), f2 = floorf(s2);
    float w1x = s0 - f0, w1y = s1 - f1, w1z = s2 - f2;   // == s % 1
    float w0x = 1.0f - w1x, w0y = 1.0f - w1y, w0z = 1.0f - w1z;
    int i0 = (int)f0, i1 = (int)f1, i2 = (int)f2;
    int ix0 = min(max(i0, 0), 63), ix1 = min(max(i0 + 1, 0), 63);
    int iy0 = min(max(i1, 0), 31), iy1 = min(max(i1 + 1, 0), 31);
    int iz0 = min(max(i2, 0), 31), iz1 = min(max(i2 + 1, 0), 31);
    int bx0 = ix0 << 10, bx1 = ix1 << 10;
    int by0 = iy0 << 5,  by1 = iy1 << 5;

    // ---- 8 corner gathers (L2-direct) into named scalars ----
    const float* p0 = plist + (bx0 + by0 + iz0) * 3;
    const float* p1 = plist + (bx0 + by0 + iz1) * 3;
    const float* p2 = plist + (bx0 + by1 + iz0) * 3;
    const float* p3 = plist + (bx0 + by1 + iz1) * 3;
    const float* p4 = plist + (bx1 + by0 + iz0) * 3;
    const float* p5 = plist + (bx1 + by0 + iz1) * 3;
    const float* p6 = plist + (bx1 + by1 + iz0) * 3;
    const float* p7 = plist + (bx1 + by1 + iz1) * 3;
    float c0x = ld_l2(p0 + 0), c0y = ld_l2(p0 + 1), c0z = ld_l2(p0 + 2);
    float c1x = ld_l2(p1 + 0), c1y = ld_l2(p1 + 1), c1z = ld_l2(p1 + 2);
    float c2x = ld_l2(p2 + 0), c2y = ld_l2(p2 + 1), c2z = ld_l2(p2 + 2);
    float c3x = ld_l2(p3 + 0), c3y = ld_l2(p3 + 1), c3z = ld_l2(p3 + 2);
    float c4x = ld_l2(p4 + 0), c4y = ld_l2(p4 + 1), c4z = ld_l2(p4 + 2);
    float c5x = ld_l2(p5 + 0), c5y = ld_l2(p5 + 1), c5z = ld_l2(p5 + 2);
    float c6x = ld_l2(p6 + 0), c6y = ld_l2(p6 + 1), c6z = ld_l2(p6 + 2);
    float c7x = ld_l2(p7 + 0), c7y = ld_l2(p7 + 1), c7z = ld_l2(p7 + 2);

    float w000 = w0x * w0y * w0z;
    float w001 = w0x * w0y * w1z;
    float w010 = w0x * w1y * w0z;
    float w011 = w0x * w1y * w1z;
    float w100 = w1x * w0y * w0z;
    float w101 = w1x * w0y * w1z;
    float w110 = w1x * w1y * w0z;
    float w111 = w1x * w1y * w1z;

    float a0 = c0x * w000 + c1x * w001 + c2x * w010 + c3x * w011
             + c4x * w100 + c5x * w101 + c6x * w110 + c7x * w111;
    float a1 = c0y * w000 + c1y * w001 + c2y * w010 + c3y * w011
             + c4y * w100 + c5y * w101 + c6y * w110 + c7y * w111;
    float a2 = c0z * w000 + c1z * w001 + c2z * w010 + c3z * w011
             + c4z * w100 + c5z * w101 + c6z * w110 + c7z * w111;

    a0 = fminf(fmaxf(a0, 0.0f), 1.0f);
    a1 = fminf(fmaxf(a1, 0.0f), 1.0f);
    a2 = fminf(fmaxf(a2, 0.0f), 1.0f);
    // ---- LUV -> XYZ ----
    float L2 = a0 * 100.0f;
    float uu = a1 * 200.0f - 100.0f;
    float vv = a2 * 200.0f - 100.0f;
    float idl = 1.0f / (13.0f * L2 + 1e-10f);
    float up2 = uu * idl + 0.1978f;
    float vp2 = vv * idl + 0.4683f;
    float y2;
    if (L2 <= 8.0f) {
        y2 = L2 * 0.0011070564598794539f;       // (3/29)^3
    } else {
        float t = (L2 + 16.0f) * (1.0f / 116.0f);
        y2 = t * t * t;
    }
    float dn = 4.0f * vp2 + 1e-10f;
    float x2 = y2 * 9.0f * up2 / dn;
    float z2 = y2 * (12.0f - 3.0f * up2 - 20.0f * vp2) / dn;
    x2 = fminf(fmaxf(x2, 0.0f), 1.1f);
    float y2c = fminf(fmaxf(y2, 0.0f), 1.1f);
    z2 = fminf(fmaxf(z2, 0.0f), 1.1f);
    // ---- XYZ -> sRGB ----
    float rr = 3.2406f * x2 - 1.5372f * y2c - 0.4986f * z2;
    float gg = -0.9689f * x2 + 1.8758f * y2c + 0.0415f * z2;
    float b2 = 0.0557f * x2 - 0.2040f * y2c + 1.0570f * z2;

    float* o = out + (size_t)n * (3 * HW_) + pv;
    o[0]       = enc_srgb(rr);
    o[HW_]     = enc_srgb(gg);
    o[2 * HW_] = enc_srgb(b2);
}

extern "C" void kernel_launch(void* const* d_in, const int* in_sizes, int n_in,
                              void* d_out, int out_size, void* d_ws, size_t ws_size,
                              hipStream_t stream) {
    const float* imgs   = (const float*)d_in[0];   // (64,3,224,224) f32
    const float* params = (const float*)d_in[1];   // (64,64,32,32,3) f32
    float* out = (float*)d_out;                    // (64,3,224,224) f32
    // 64 images * 50176 px/image = 3211264 threads = 12544 blocks * 256
    cieluv_k10<<<dim3(12544), dim3(256), 0, stream>>>(imgs, params, out);
}

// Round 11
// 81.892 us; speedup vs baseline: 3.9739x; 3.9739x over previous
//
#include <hip/hip_runtime.h>

#define HW_   50176      // 224*224
#define PSTR_ 196608     // 64*32*32*3 floats per image
#define NENT_ 65536      // 64*32*32 entries per image

typedef _Float16 h4 __attribute__((ext_vector_type(4)));

__device__ __forceinline__ float fpow(float x, float e) {
    // x > 0 guaranteed by callers; v_log_f32 is log2, v_exp_f32 is exp2
    return __builtin_amdgcn_exp2f(e * __builtin_amdgcn_logf(x));
}

__device__ __forceinline__ float srgb_lin(float c) {
    return c < 0.04045f ? c * (1.0f / 12.92f)
                        : fpow((c + 0.055f) * (1.0f / 1.055f), 2.4f);
}

__device__ __forceinline__ float enc_srgb(float c) {
    float e = (c < 0.0031308f)
                  ? 12.92f * c
                  : 1.055f * fpow(fmaxf(c, 1e-10f), 1.0f / 2.4f) - 0.055f;
    return fminf(fmaxf(e, 0.0f), 1.0f);
}

// ---- pre-pass: f32 LUT -> fp16 DELTA-from-identity, padded 8B/entry ----
__global__ __launch_bounds__(256) void lut_delta_k11(
    const float* __restrict__ params,
    _Float16* __restrict__ lut)
{
    int gid = blockIdx.x * 256 + threadIdx.x;   // 0 .. 64*65536-1
    int idx = gid & (NENT_ - 1);
    int ix = idx >> 10, iy = (idx >> 5) & 31, iz = idx & 31;
    float gx = (float)ix * (1.0f / 63.0f);
    float gy = (float)iy * (1.0f / 31.0f);
    float gz = (float)iz * (1.0f / 31.0f);
    const float* p = params + (size_t)gid * 3;
    h4 v;
    v.x = (_Float16)(p[0] - gx);
    v.y = (_Float16)(p[1] - gy);
    v.z = (_Float16)(p[2] - gz);
    v.w = (_Float16)0.f;
    *(h4*)(lut + (size_t)gid * 4) = v;
}

// MODE 0: fp32 direct gathers (proven r8). MODE 1: fp16-delta gathers
// (16 dwords/px) + exact fp32 fallback for dark pixels (a0 < 0.14).
template <int MODE>
__global__ __launch_bounds__(256) void cieluv_k11(
    const float* __restrict__ imgs,
    const float* __restrict__ params,
    const _Float16* __restrict__ lut,
    float* __restrict__ out)
{
    // XCD-chunk swizzle (bijective: gridDim.x=12544 divisible by 8)
    int bid = blockIdx.x;
    int cpx = gridDim.x >> 3;                 // 1568
    int b   = (bid & 7) * cpx + (bid >> 3);

    int vi = b * 256 + threadIdx.x;           // pixel index (1 px/thread)
    int n  = vi / HW_;                        // image
    int pv = vi - n * HW_;                    // pixel offset within plane

    const float* img = imgs + (size_t)n * (3 * HW_) + pv;
    float rr_in = img[0];
    float gg_in = img[HW_];
    float bb_in = img[2 * HW_];
    const float* __restrict__ plist = params + (size_t)n * PSTR_;

    // ---- sRGB -> linear ----
    float r = srgb_lin(rr_in);
    float g = srgb_lin(gg_in);
    float bl = srgb_lin(bb_in);
    // ---- linear RGB -> XYZ ----
    float x = 0.4124f * r + 0.3576f * g + 0.1805f * bl;
    float y = 0.2126f * r + 0.7152f * g + 0.0722f * bl;
    float z = 0.0193f * r + 0.1192f * g + 0.9504f * bl;
    // ---- XYZ -> LUV (normalized) ----
    float inv = 1.0f / (x + 15.0f * y + 3.0f * z + 1e-10f);
    float up = 4.0f * x * inv;
    float vp = 9.0f * y * inv;
    float L = (y < 0.008856451679035631f)
                  ? 903.2962962962963f * y
                  : 116.0f * fpow(fmaxf(y, 1e-10f), 1.0f / 3.0f) - 16.0f;
    float u = 13.0f * L * (up - 0.1978f);
    float v = 13.0f * L * (vp - 0.4683f);
    float c0 = L * 0.01f;
    float c1 = (u + 100.0f) * 0.005f;
    float c2 = (v + 100.0f) * 0.005f;
    // ---- trilinear LUT coords (RX=64, RY=32, RZ=32) ----
    float s0 = c0 * 63.0f, s1 = c1 * 31.0f, s2 = c2 * 31.0f;
    float f0 = floorf(s0), f1 = floorf(s1), f2 = floorf(s2);
    float w1x = s0 - f0, w1y = s1 - f1, w1z = s2 - f2;   // == s % 1
    float w0x = 1.0f - w1x, w0y = 1.0f - w1y, w0z = 1.0f - w1z;
    int i0 = (int)f0, i1 = (int)f1, i2 = (int)f2;
    int ix0 = min(max(i0, 0), 63), ix1 = min(max(i0 + 1, 0), 63);
    int iy0 = min(max(i1, 0), 31), iy1 = min(max(i1 + 1, 0), 31);
    int iz0 = min(max(i2, 0), 31), iz1 = min(max(i2 + 1, 0), 31);
    int bx0 = ix0 << 10, bx1 = ix1 << 10;
    int by0 = iy0 << 5,  by1 = iy1 << 5;

    float w000 = w0x * w0y * w0z;
    float w001 = w0x * w0y * w1z;
    float w010 = w0x * w1y * w0z;
    float w011 = w0x * w1y * w1z;
    float w100 = w1x * w0y * w0z;
    float w101 = w1x * w0y * w1z;
    float w110 = w1x * w1y * w0z;
    float w111 = w1x * w1y * w1z;

    float a0, a1, a2;

    if (MODE == 1) {
        // ---- 8 corner gathers of fp16 deltas (dwordx2 each) ----
        const _Float16* __restrict__ ph = lut + (size_t)n * (NENT_ * 4);
        h4 V0 = *(const h4*)(ph + (size_t)(bx0 + by0 + iz0) * 4);
        h4 V1 = *(const h4*)(ph + (size_t)(bx0 + by0 + iz1) * 4);
        h4 V2 = *(const h4*)(ph + (size_t)(bx0 + by1 + iz0) * 4);
        h4 V3 = *(const h4*)(ph + (size_t)(bx0 + by1 + iz1) * 4);
        h4 V4 = *(const h4*)(ph + (size_t)(bx1 + by0 + iz0) * 4);
        h4 V5 = *(const h4*)(ph + (size_t)(bx1 + by0 + iz1) * 4);
        h4 V6 = *(const h4*)(ph + (size_t)(bx1 + by1 + iz0) * 4);
        h4 V7 = *(const h4*)(ph + (size_t)(bx1 + by1 + iz1) * 4);

        // analytic identity part (exactly ref's interp of identity corners)
        float gx = (w0x * (float)ix0 + w1x * (float)ix1) * (1.0f / 63.0f);
        float gy = (w0y * (float)iy0 + w1y * (float)iy1) * (1.0f / 31.0f);
        float gz = (w0z * (float)iz0 + w1z * (float)iz1) * (1.0f / 31.0f);

        float d0 = (float)V0.x * w000 + (float)V1.x * w001 + (float)V2.x * w010 + (float)V3.x * w011
                 + (float)V4.x * w100 + (float)V5.x * w101 + (float)V6.x * w110 + (float)V7.x * w111;
        float d1 = (float)V0.y * w000 + (float)V1.y * w001 + (float)V2.y * w010 + (float)V3.y * w011
                 + (float)V4.y * w100 + (float)V5.y * w101 + (float)V6.y * w110 + (float)V7.y * w111;
        float d2 = (float)V0.z * w000 + (float)V1.z * w001 + (float)V2.z * w010 + (float)V3.z * w011
                 + (float)V4.z * w100 + (float)V5.z * w101 + (float)V6.z * w110 + (float)V7.z * w111;

        a0 = gx + d0;
        a1 = gy + d1;
        a2 = gz + d2;

        // dark pixels: dn=4*vp2+eps can approach 0 only for L2 <~ 12 ->
        // exact fp32 recompute (ref-identical) for a0 < 0.14 (~5% of px)
        if (a0 < 0.14f) {
            const float* p0 = plist + (bx0 + by0 + iz0) * 3;
            const float* p1 = plist + (bx0 + by0 + iz1) * 3;
            const float* p2 = plist + (bx0 + by1 + iz0) * 3;
            const float* p3 = plist + (bx0 + by1 + iz1) * 3;
            const float* p4 = plist + (bx1 + by0 + iz0) * 3;
            const float* p5 = plist + (bx1 + by0 + iz1) * 3;
            const float* p6 = plist + (bx1 + by1 + iz0) * 3;
            const float* p7 = plist + (bx1 + by1 + iz1) * 3;
            a0 = p0[0] * w000 + p1[0] * w001 + p2[0] * w010 + p3[0] * w011
               + p4[0] * w100 + p5[0] * w101 + p6[0] * w110 + p7[0] * w111;
            a1 = p0[1] * w000 + p1[1] * w001 + p2[1] * w010 + p3[1] * w011
               + p4[1] * w100 + p5[1] * w101 + p6[1] * w110 + p7[1] * w111;
            a2 = p0[2] * w000 + p1[2] * w001 + p2[2] * w010 + p3[2] * w011
               + p4[2] * w100 + p5[2] * w101 + p6[2] * w110 + p7[2] * w111;
        }
    } else {
        const float* p0 = plist + (bx0 + by0 + iz0) * 3;
        const float* p1 = plist + (bx0 + by0 + iz1) * 3;
        const float* p2 = plist + (bx0 + by1 + iz0) * 3;
        const float* p3 = plist + (bx0 + by1 + iz1) * 3;
        const float* p4 = plist + (bx1 + by0 + iz0) * 3;
        const float* p5 = plist + (bx1 + by0 + iz1) * 3;
        const float* p6 = plist + (bx1 + by1 + iz0) * 3;
        const float* p7 = plist + (bx1 + by1 + iz1) * 3;
        a0 = p0[0] * w000 + p1[0] * w001 + p2[0] * w010 + p3[0] * w011
           + p4[0] * w100 + p5[0] * w101 + p6[0] * w110 + p7[0] * w111;
        a1 = p0[1] * w000 + p1[1] * w001 + p2[1] * w010 + p3[1] * w011
           + p4[1] * w100 + p5[1] * w101 + p6[1] * w110 + p7[1] * w111;
        a2 = p0[2] * w000 + p1[2] * w001 + p2[2] * w010 + p3[2] * w011
           + p4[2] * w100 + p5[2] * w101 + p6[2] * w110 + p7[2] * w111;
    }

    a0 = fminf(fmaxf(a0, 0.0f), 1.0f);
    a1 = fminf(fmaxf(a1, 0.0f), 1.0f);
    a2 = fminf(fmaxf(a2, 0.0f), 1.0f);
    // ---- LUV -> XYZ ----
    float L2 = a0 * 100.0f;
    float uu = a1 * 200.0f - 100.0f;
    float vv = a2 * 200.0f - 100.0f;
    float idl = 1.0f / (13.0f * L2 + 1e-10f);
    float up2 = uu * idl + 0.1978f;
    float vp2 = vv * idl + 0.4683f;
    float y2;
    if (L2 <= 8.0f) {
        y2 = L2 * 0.0011070564598794539f;       // (3/29)^3
    } else {
        float t = (L2 + 16.0f) * (1.0f / 116.0f);
        y2 = t * t * t;
    }
    float dn = 4.0f * vp2 + 1e-10f;
    float x2 = y2 * 9.0f * up2 / dn;
    float z2 = y2 * (12.0f - 3.0f * up2 - 20.0f * vp2) / dn;
    x2 = fminf(fmaxf(x2, 0.0f), 1.1f);
    float y2c = fminf(fmaxf(y2, 0.0f), 1.1f);
    z2 = fminf(fmaxf(z2, 0.0f), 1.1f);
    // ---- XYZ -> sRGB ----
    float rr = 3.2406f * x2 - 1.5372f * y2c - 0.4986f * z2;
    float gg = -0.9689f * x2 + 1.8758f * y2c + 0.0415f * z2;
    float b2 = 0.0557f * x2 - 0.2040f * y2c + 1.0570f * z2;

    float* o = out + (size_t)n * (3 * HW_) + pv;
    o[0]       = enc_srgb(rr);
    o[HW_]     = enc_srgb(gg);
    o[2 * HW_] = enc_srgb(b2);
}

extern "C" void kernel_launch(void* const* d_in, const int* in_sizes, int n_in,
                              void* d_out, int out_size, void* d_ws, size_t ws_size,
                              hipStream_t stream) {
    const float* imgs   = (const float*)d_in[0];   // (64,3,224,224) f32
    const float* params = (const float*)d_in[1];   // (64,64,32,32,3) f32
    float* out = (float*)d_out;                    // (64,3,224,224) f32

    const size_t lut_bytes = (size_t)64 * NENT_ * 4 * sizeof(_Float16); // 33.5 MB
    if (ws_size >= lut_bytes) {
        _Float16* lut = (_Float16*)d_ws;
        lut_delta_k11<<<dim3(16384), dim3(256), 0, stream>>>(params, lut);
        cieluv_k11<1><<<dim3(12544), dim3(256), 0, stream>>>(imgs, params, lut, out);
    } else {
        // fallback: proven r8 path (fp32 gathers)
        cieluv_k11<0><<<dim3(12544), dim3(256), 0, stream>>>(imgs, params, nullptr, out);
    }
}

// Round 12
// 73.006 us; speedup vs baseline: 4.4576x; 1.1217x over previous
//
#include <hip/hip_runtime.h>

#define HW_   50176      // 224*224
#define PSTR_ 196608     // 64*32*32*3 floats per image
#define NENT_ 65536      // 64*32*32 entries per image

__device__ __forceinline__ float fpow(float x, float e) {
    // x > 0 guaranteed by callers; v_log_f32 is log2, v_exp_f32 is exp2
    return __builtin_amdgcn_exp2f(e * __builtin_amdgcn_logf(x));
}

__device__ __forceinline__ float srgb_lin(float c) {
    return c < 0.04045f ? c * (1.0f / 12.92f)
                        : fpow((c + 0.055f) * (1.0f / 1.055f), 2.4f);
}

__device__ __forceinline__ float enc_srgb(float c) {
    float e = (c < 0.0031308f)
                  ? 12.92f * c
                  : 1.055f * fpow(fmaxf(c, 1e-10f), 1.0f / 2.4f) - 0.055f;
    return fminf(fmaxf(e, 0.0f), 1.0f);
}

// ---- pre-pass: f32 LUT -> u32 packed delta (x:10,y:11,z:11), 2x2x2-blocked ----
__global__ __launch_bounds__(256) void lut_pack_k12(
    const float* __restrict__ params,
    unsigned int* __restrict__ lut)
{
    int gid = blockIdx.x * 256 + threadIdx.x;   // 0 .. 64*65536-1
    int idx = gid & (NENT_ - 1);
    int n   = gid >> 16;
    int ix = idx >> 10, iy = (idx >> 5) & 31, iz = idx & 31;
    const float* p = params + (size_t)gid * 3;
    float dx = p[0] - (float)ix * (1.0f / 63.0f);
    float dy = p[1] - (float)iy * (1.0f / 31.0f);
    float dz = p[2] - (float)iz * (1.0f / 31.0f);
    // quantize over [-0.0625, 0.0625]
    int qx = (int)floorf((dx + 0.0625f) * 8192.0f  + 0.5f);   // 10 bits
    int qy = (int)floorf((dy + 0.0625f) * 16384.0f + 0.5f);   // 11 bits
    int qz = (int)floorf((dz + 0.0625f) * 16384.0f + 0.5f);   // 11 bits
    qx = min(max(qx, 0), 1023);
    qy = min(max(qy, 0), 2047);
    qz = min(max(qz, 0), 2047);
    unsigned int u = (unsigned)qx | ((unsigned)qy << 10) | ((unsigned)qz << 21);
    // blocked layout: block B = (ix/2, iy/2, iz/2), 8 entries (32B) contiguous
    int B = ((ix >> 1) << 8) | ((iy >> 1) << 4) | (iz >> 1);
    int o = ((ix & 1) << 2) | ((iy & 1) << 1) | (iz & 1);
    lut[((size_t)n << 16) + (size_t)((B << 3) + o)] = u;
}

__device__ __forceinline__ float dec_x(unsigned u) {
    return (float)(u & 1023u) * (1.0f / 8192.0f) - 0.0625f;
}
__device__ __forceinline__ float dec_y(unsigned u) {
    return (float)((u >> 10) & 2047u) * (1.0f / 16384.0f) - 0.0625f;
}
__device__ __forceinline__ float dec_z(unsigned u) {
    return (float)(u >> 21) * (1.0f / 16384.0f) - 0.0625f;
}

// MODE 0: fp32 direct gathers (proven r8). MODE 1: packed-blocked u32 gathers
// + exact fp32 fallback for dark pixels (a0 < 0.14).
template <int MODE>
__global__ __launch_bounds__(256) void cieluv_k12(
    const float* __restrict__ imgs,
    const float* __restrict__ params,
    const unsigned int* __restrict__ lut,
    float* __restrict__ out)
{
    // XCD-chunk swizzle (bijective: gridDim.x=12544 divisible by 8)
    int bid = blockIdx.x;
    int cpx = gridDim.x >> 3;                 // 1568
    int b   = (bid & 7) * cpx + (bid >> 3);

    int vi = b * 256 + threadIdx.x;           // pixel index (1 px/thread)
    int n  = vi / HW_;                        // image
    int pv = vi - n * HW_;                    // pixel offset within plane

    const float* img = imgs + (size_t)n * (3 * HW_) + pv;
    float rr_in = img[0];
    float gg_in = img[HW_];
    float bb_in = img[2 * HW_];
    const float* __restrict__ plist = params + (size_t)n * PSTR_;

    // ---- sRGB -> linear ----
    float r = srgb_lin(rr_in);
    float g = srgb_lin(gg_in);
    float bl = srgb_lin(bb_in);
    // ---- linear RGB -> XYZ ----
    float x = 0.4124f * r + 0.3576f * g + 0.1805f * bl;
    float y = 0.2126f * r + 0.7152f * g + 0.0722f * bl;
    float z = 0.0193f * r + 0.1192f * g + 0.9504f * bl;
    // ---- XYZ -> LUV (normalized) ----
    float inv = 1.0f / (x + 15.0f * y + 3.0f * z + 1e-10f);
    float up = 4.0f * x * inv;
    float vp = 9.0f * y * inv;
    float L = (y < 0.008856451679035631f)
                  ? 903.2962962962963f * y
                  : 116.0f * fpow(fmaxf(y, 1e-10f), 1.0f / 3.0f) - 16.0f;
    float u = 13.0f * L * (up - 0.1978f);
    float v = 13.0f * L * (vp - 0.4683f);
    // ---- trilinear LUT coords (RX=64, RY=32, RZ=32) ----
    float s0 = L * 0.63f;                 // (L/100)*63
    float s1 = (u + 100.0f) * 0.155f;     // ((u+100)/200)*31
    float s2 = (v + 100.0f) * 0.155f;
    float f0 = floorf(s0), f1 = floorf(s1), f2 = floorf(s2);
    float w1x = s0 - f0, w1y = s1 - f1, w1z = s2 - f2;   // == s % 1
    float w0x = 1.0f - w1x, w0y = 1.0f - w1y, w0z = 1.0f - w1z;
    int i0 = (int)f0, i1 = (int)f1, i2 = (int)f2;
    int ix0 = min(max(i0, 0), 63), ix1 = min(max(i0 + 1, 0), 63);
    int iy0 = min(max(i1, 0), 31), iy1 = min(max(i1 + 1, 0), 31);
    int iz0 = min(max(i2, 0), 31), iz1 = min(max(i2 + 1, 0), 31);

    float w000 = w0x * w0y * w0z;
    float w001 = w0x * w0y * w1z;
    float w010 = w0x * w1y * w0z;
    float w011 = w0x * w1y * w1z;
    float w100 = w1x * w0y * w0z;
    float w101 = w1x * w0y * w1z;
    float w110 = w1x * w1y * w0z;
    float w111 = w1x * w1y * w1z;

    float a0, a1, a2;

    if (MODE == 1) {
        const unsigned int* __restrict__ ph = lut + ((size_t)n << 16);
        int xb0 = (ix0 >> 1) << 8, xb1 = (ix1 >> 1) << 8;
        int yb0 = (iy0 >> 1) << 4, yb1 = (iy1 >> 1) << 4;
        int zb0 = iz0 >> 1,        zb1 = iz1 >> 1;
        int xo0 = (ix0 & 1) << 2,  xo1 = (ix1 & 1) << 2;
        int yo0 = (iy0 & 1) << 1,  yo1 = (iy1 & 1) << 1;
        int zo0 = iz0 & 1,         zo1 = iz1 & 1;

        unsigned U0 = ph[((xb0 + yb0 + zb0) << 3) + (xo0 + yo0 + zo0)];
        unsigned U1 = ph[((xb0 + yb0 + zb1) << 3) + (xo0 + yo0 + zo1)];
        unsigned U2 = ph[((xb0 + yb1 + zb0) << 3) + (xo0 + yo1 + zo0)];
        unsigned U3 = ph[((xb0 + yb1 + zb1) << 3) + (xo0 + yo1 + zo1)];
        unsigned U4 = ph[((xb1 + yb0 + zb0) << 3) + (xo1 + yo0 + zo0)];
        unsigned U5 = ph[((xb1 + yb0 + zb1) << 3) + (xo1 + yo0 + zo1)];
        unsigned U6 = ph[((xb1 + yb1 + zb0) << 3) + (xo1 + yo1 + zo0)];
        unsigned U7 = ph[((xb1 + yb1 + zb1) << 3) + (xo1 + yo1 + zo1)];

        // analytic identity part (exactly ref's interp of identity corners)
        float gx = (w0x * (float)ix0 + w1x * (float)ix1) * (1.0f / 63.0f);
        float gy = (w0y * (float)iy0 + w1y * (float)iy1) * (1.0f / 31.0f);
        float gz = (w0z * (float)iz0 + w1z * (float)iz1) * (1.0f / 31.0f);

        float d0 = dec_x(U0) * w000 + dec_x(U1) * w001 + dec_x(U2) * w010 + dec_x(U3) * w011
                 + dec_x(U4) * w100 + dec_x(U5) * w101 + dec_x(U6) * w110 + dec_x(U7) * w111;
        float d1 = dec_y(U0) * w000 + dec_y(U1) * w001 + dec_y(U2) * w010 + dec_y(U3) * w011
                 + dec_y(U4) * w100 + dec_y(U5) * w101 + dec_y(U6) * w110 + dec_y(U7) * w111;
        float d2 = dec_z(U0) * w000 + dec_z(U1) * w001 + dec_z(U2) * w010 + dec_z(U3) * w011
                 + dec_z(U4) * w100 + dec_z(U5) * w101 + dec_z(U6) * w110 + dec_z(U7) * w111;

        a0 = gx + d0;
        a1 = gy + d1;
        a2 = gz + d2;

        // dark pixels: exact fp32 recompute (ref-identical) for a0 < 0.14
        if (a0 < 0.14f) {
            int bx0 = ix0 << 10, bx1 = ix1 << 10;
            int by0 = iy0 << 5,  by1 = iy1 << 5;
            const float* p0 = plist + (bx0 + by0 + iz0) * 3;
            const float* p1 = plist + (bx0 + by0 + iz1) * 3;
            const float* p2 = plist + (bx0 + by1 + iz0) * 3;
            const float* p3 = plist + (bx0 + by1 + iz1) * 3;
            const float* p4 = plist + (bx1 + by0 + iz0) * 3;
            const float* p5 = plist + (bx1 + by0 + iz1) * 3;
            const float* p6 = plist + (bx1 + by1 + iz0) * 3;
            const float* p7 = plist + (bx1 + by1 + iz1) * 3;
            a0 = p0[0] * w000 + p1[0] * w001 + p2[0] * w010 + p3[0] * w011
               + p4[0] * w100 + p5[0] * w101 + p6[0] * w110 + p7[0] * w111;
            a1 = p0[1] * w000 + p1[1] * w001 + p2[1] * w010 + p3[1] * w011
               + p4[1] * w100 + p5[1] * w101 + p6[1] * w110 + p7[1] * w111;
            a2 = p0[2] * w000 + p1[2] * w001 + p2[2] * w010 + p3[2] * w011
               + p4[2] * w100 + p5[2] * w101 + p6[2] * w110 + p7[2] * w111;
        }
    } else {
        int bx0 = ix0 << 10, bx1 = ix1 << 10;
        int by0 = iy0 << 5,  by1 = iy1 << 5;
        const float* p0 = plist + (bx0 + by0 + iz0) * 3;
        const float* p1 = plist + (bx0 + by0 + iz1) * 3;
        const float* p2 = plist + (bx0 + by1 + iz0) * 3;
        const float* p3 = plist + (bx0 + by1 + iz1) * 3;
        const float* p4 = plist + (bx1 + by0 + iz0) * 3;
        const float* p5 = plist + (bx1 + by0 + iz1) * 3;
        const float* p6 = plist + (bx1 + by1 + iz0) * 3;
        const float* p7 = plist + (bx1 + by1 + iz1) * 3;
        a0 = p0[0] * w000 + p1[0] * w001 + p2[0] * w010 + p3[0] * w011
           + p4[0] * w100 + p5[0] * w101 + p6[0] * w110 + p7[0] * w111;
        a1 = p0[1] * w000 + p1[1] * w001 + p2[1] * w010 + p3[1] * w011
           + p4[1] * w100 + p5[1] * w101 + p6[1] * w110 + p7[1] * w111;
        a2 = p0[2] * w000 + p1[2] * w001 + p2[2] * w010 + p3[2] * w011
           + p4[2] * w100 + p5[2] * w101 + p6[2] * w110 + p7[2] * w111;
    }

    a0 = fminf(fmaxf(a0, 0.0f), 1.0f);
    a1 = fminf(fmaxf(a1, 0.0f), 1.0f);
    a2 = fminf(fmaxf(a2, 0.0f), 1.0f);
    // ---- LUV -> XYZ ----
    float L2 = a0 * 100.0f;
    float uu = a1 * 200.0f - 100.0f;
    float vv = a2 * 200.0f - 100.0f;
    float idl = 1.0f / (13.0f * L2 + 1e-10f);
    float up2 = uu * idl + 0.1978f;
    float vp2 = vv * idl + 0.4683f;
    float y2;
    if (L2 <= 8.0f) {
        y2 = L2 * 0.0011070564598794539f;       // (3/29)^3
    } else {
        float t = (L2 + 16.0f) * (1.0f / 116.0f);
        y2 = t * t * t;
    }
    float dn = 4.0f * vp2 + 1e-10f;
    float x2 = y2 * 9.0f * up2 / dn;
    float z2 = y2 * (12.0f - 3.0f * up2 - 20.0f * vp2) / dn;
    x2 = fminf(fmaxf(x2, 0.0f), 1.1f);
    float y2c = fminf(fmaxf(y2, 0.0f), 1.1f);
    z2 = fminf(fmaxf(z2, 0.0f), 1.1f);
    // ---- XYZ -> sRGB ----
    float rr = 3.2406f * x2 - 1.5372f * y2c - 0.4986f * z2;
    float gg = -0.9689f * x2 + 1.8758f * y2c + 0.0415f * z2;
    float b2 = 0.0557f * x2 - 0.2040f * y2c + 1.0570f * z2;

    float* o = out + (size_t)n * (3 * HW_) + pv;
    o[0]       = enc_srgb(rr);
    o[HW_]     = enc_srgb(gg);
    o[2 * HW_] = enc_srgb(b2);
}

extern "C" void kernel_launch(void* const* d_in, const int* in_sizes, int n_in,
                              void* d_out, int out_size, void* d_ws, size_t ws_size,
                              hipStream_t stream) {
    const float* imgs   = (const float*)d_in[0];   // (64,3,224,224) f32
    const float* params = (const float*)d_in[1];   // (64,64,32,32,3) f32
    float* out = (float*)d_out;                    // (64,3,224,224) f32

    const size_t lut_bytes = (size_t)64 * NENT_ * sizeof(unsigned int); // 16.8 MB
    if (ws_size >= lut_bytes) {
        unsigned int* lut = (unsigned int*)d_ws;
        lut_pack_k12<<<dim3(16384), dim3(256), 0, stream>>>(params, lut);
        cieluv_k12<1><<<dim3(12544), dim3(256), 0, stream>>>(imgs, params, lut, out);
    } else {
        // fallback: proven r8 path (fp32 gathers)
        cieluv_k12<0><<<dim3(12544), dim3(256), 0, stream>>>(imgs, params, nullptr, out);
    }
}

// Round 13
// 64.056 us; speedup vs baseline: 5.0804x; 1.1397x over previous
//
#include <hip/hip_runtime.h>

#define HW_   50176      // 224*224
#define PSTR_ 196608     // 64*32*32*3 floats per image

__device__ __forceinline__ float fpow(float x, float e) {
    // x > 0 guaranteed by callers; v_log_f32 is log2, v_exp_f32 is exp2
    return __builtin_amdgcn_exp2f(e * __builtin_amdgcn_logf(x));
}

__device__ __forceinline__ float srgb_lin(float c) {
    return c < 0.04045f ? c * (1.0f / 12.92f)
                        : fpow((c + 0.055f) * (1.0f / 1.055f), 2.4f);
}

__device__ __forceinline__ float enc_srgb(float c) {
    float e = (c < 0.0031308f)
                  ? 12.92f * c
                  : 1.055f * fpow(fmaxf(c, 1e-10f), 1.0f / 2.4f) - 0.055f;
    return fminf(fmaxf(e, 0.0f), 1.0f);
}

__global__ __launch_bounds__(256) void cieluv_k13(
    const float* __restrict__ imgs,
    const float* __restrict__ params,
    float* __restrict__ out)
{
    // XCD-chunk swizzle (bijective: gridDim.x=12544 divisible by 8)
    int bid = blockIdx.x;
    int cpx = gridDim.x >> 3;                 // 1568
    int b   = (bid & 7) * cpx + (bid >> 3);

    int vi = b * 256 + threadIdx.x;           // pixel index (1 px/thread)
    int n  = vi / HW_;                        // image
    int pv = vi - n * HW_;                    // pixel offset within plane

    const float* img = imgs + (size_t)n * (3 * HW_) + pv;
    float rr_in = img[0];
    float gg_in = img[HW_];
    float bb_in = img[2 * HW_];
    const float* __restrict__ plist = params + (size_t)n * PSTR_;

    // ---- sRGB -> linear ----
    float r = srgb_lin(rr_in);
    float g = srgb_lin(gg_in);
    float bl = srgb_lin(bb_in);
    // ---- linear RGB -> XYZ ----
    float x = 0.4124f * r + 0.3576f * g + 0.1805f * bl;
    float y = 0.2126f * r + 0.7152f * g + 0.0722f * bl;
    float z = 0.0193f * r + 0.1192f * g + 0.9504f * bl;
    // ---- XYZ -> LUV (normalized) ----
    float inv = 1.0f / (x + 15.0f * y + 3.0f * z + 1e-10f);
    float up = 4.0f * x * inv;
    float vp = 9.0f * y * inv;
    float L = (y < 0.008856451679035631f)
                  ? 903.2962962962963f * y
                  : 116.0f * fpow(fmaxf(y, 1e-10f), 1.0f / 3.0f) - 16.0f;
    float u = 13.0f * L * (up - 0.1978f);
    float v = 13.0f * L * (vp - 0.4683f);
    float c0 = L * 0.01f;
    float c1 = (u + 100.0f) * 0.005f;
    float c2 = (v + 100.0f) * 0.005f;
    // ---- trilinear LUT (RX=64, RY=32, RZ=32) ----
    float s0 = c0 * 63.0f, s1 = c1 * 31.0f, s2 = c2 * 31.0f;
    float f0 = floorf(s0), f1 = floorf(s1), f2 = floorf(s2);
    float w1x = s0 - f0, w1y = s1 - f1, w1z = s2 - f2;   // == s % 1
    float w0x = 1.0f - w1x, w0y = 1.0f - w1y, w0z = 1.0f - w1z;
    int i0 = (int)f0, i1 = (int)f1, i2 = (int)f2;
    int ix0 = min(max(i0, 0), 63), ix1 = min(max(i0 + 1, 0), 63);
    int iy0 = min(max(i1, 0), 31), iy1 = min(max(i1 + 1, 0), 31);
    int iz0 = min(max(i2, 0), 31), iz1 = min(max(i2 + 1, 0), 31);
    int bx0 = ix0 << 10, bx1 = ix1 << 10;
    int by0 = iy0 << 5,  by1 = iy1 << 5;

    // ---- 8 corner gathers into named scalars ----
    const float* p0 = plist + (bx0 + by0 + iz0) * 3;
    const float* p1 = plist + (bx0 + by0 + iz1) * 3;
    const float* p2 = plist + (bx0 + by1 + iz0) * 3;
    const float* p3 = plist + (bx0 + by1 + iz1) * 3;
    const float* p4 = plist + (bx1 + by0 + iz0) * 3;
    const float* p5 = plist + (bx1 + by0 + iz1) * 3;
    const float* p6 = plist + (bx1 + by1 + iz0) * 3;
    const float* p7 = plist + (bx1 + by1 + iz1) * 3;
    float c0x = p0[0], c0y = p0[1], c0z = p0[2];
    float c1x = p1[0], c1y = p1[1], c1z = p1[2];
    float c2x = p2[0], c2y = p2[1], c2z = p2[2];
    float c3x = p3[0], c3y = p3[1], c3z = p3[2];
    float c4x = p4[0], c4y = p4[1], c4z = p4[2];
    float c5x = p5[0], c5y = p5[1], c5z = p5[2];
    float c6x = p6[0], c6y = p6[1], c6z = p6[2];
    float c7x = p7[0], c7y = p7[1], c7z = p7[2];

    float w000 = w0x * w0y * w0z;
    float w001 = w0x * w0y * w1z;
    float w010 = w0x * w1y * w0z;
    float w011 = w0x * w1y * w1z;
    float w100 = w1x * w0y * w0z;
    float w101 = w1x * w0y * w1z;
    float w110 = w1x * w1y * w0z;
    float w111 = w1x * w1y * w1z;

    float a0 = c0x * w000 + c1x * w001 + c2x * w010 + c3x * w011
             + c4x * w100 + c5x * w101 + c6x * w110 + c7x * w111;
    float a1 = c0y * w000 + c1y * w001 + c2y * w010 + c3y * w011
             + c4y * w100 + c5y * w101 + c6y * w110 + c7y * w111;
    float a2 = c0z * w000 + c1z * w001 + c2z * w010 + c3z * w011
             + c4z * w100 + c5z * w101 + c6z * w110 + c7z * w111;

    a0 = fminf(fmaxf(a0, 0.0f), 1.0f);
    a1 = fminf(fmaxf(a1, 0.0f), 1.0f);
    a2 = fminf(fmaxf(a2, 0.0f), 1.0f);
    // ---- LUV -> XYZ ----
    float L2 = a0 * 100.0f;
    float uu = a1 * 200.0f - 100.0f;
    float vv = a2 * 200.0f - 100.0f;
    float idl = 1.0f / (13.0f * L2 + 1e-10f);
    float up2 = uu * idl + 0.1978f;
    float vp2 = vv * idl + 0.4683f;
    float y2;
    if (L2 <= 8.0f) {
        y2 = L2 * 0.0011070564598794539f;       // (3/29)^3
    } else {
        float t = (L2 + 16.0f) * (1.0f / 116.0f);
        y2 = t * t * t;
    }
    float dn = 4.0f * vp2 + 1e-10f;
    float x2 = y2 * 9.0f * up2 / dn;
    float z2 = y2 * (12.0f - 3.0f * up2 - 20.0f * vp2) / dn;
    x2 = fminf(fmaxf(x2, 0.0f), 1.1f);
    float y2c = fminf(fmaxf(y2, 0.0f), 1.1f);
    z2 = fminf(fmaxf(z2, 0.0f), 1.1f);
    // ---- XYZ -> sRGB ----
    float rr = 3.2406f * x2 - 1.5372f * y2c - 0.4986f * z2;
    float gg = -0.9689f * x2 + 1.8758f * y2c + 0.0415f * z2;
    float b2 = 0.0557f * x2 - 0.2040f * y2c + 1.0570f * z2;

    float* o = out + (size_t)n * (3 * HW_) + pv;
    o[0]       = enc_srgb(rr);
    o[HW_]     = enc_srgb(gg);
    o[2 * HW_] = enc_srgb(b2);
}

extern "C" void kernel_launch(void* const* d_in, const int* in_sizes, int n_in,
                              void* d_out, int out_size, void* d_ws, size_t ws_size,
                              hipStream_t stream) {
    const float* imgs   = (const float*)d_in[0];   // (64,3,224,224) f32
    const float* params = (const float*)d_in[1];   // (64,64,32,32,3) f32
    float* out = (float*)d_out;                    // (64,3,224,224) f32
    // 64 images * 50176 px/image = 3211264 threads = 12544 blocks * 256
    cieluv_k13<<<dim3(12544), dim3(256), 0, stream>>>(imgs, params, out);
}